// Round 11
// baseline (60.913 us; speedup 1.0000x reference)
//
#include <hip/hip_runtime.h>
#include <math.h>

#define IMG_H 512
#define IMG_W 512
#define TW 256               // output cols per block
#define TH 4                 // output rows per block
#define KR 5                 // radius
#define KS 11                // taps
#define NR (TH + 2 * KR)     // 14 input rows per band
#define NSTRIP (TW + 2 * KR) // 266 staged columns (elems)
#define LWE 268              // padded elems per row
#define NTHREADS 256
#define NXT (IMG_W / TW)     // 2
#define NBANDS (IMG_H / TH)  // 128
#define NPLANES 48
#define NBLK (NXT * NBANDS * NPLANES)   // 12288, divisible by 8

typedef float f32x2 __attribute__((ext_vector_type(2)));
typedef float f32x4 __attribute__((ext_vector_type(4)));

struct W22 { float w[2 * KS]; };   // w[2k] == w[2k+1] == gaussian tap k

// 16B-elem XOR swizzle: elem e (one f32x4). Spreads bank quads so phase-B
// b128 reads (64B lane stride) and phase-A writes are conflict-free.
__device__ __forceinline__ int swz(int e) { return e ^ ((e >> 3) & 7); }

// Fused SSIM tile kernel: one 256x4 output tile per block, 256 threads.
// Single LDS field per staged elem: (conv_v(a), conv_v(b), conv_v(a^2+b^2),
// conv_v(ab)) as f32x4. 17.2 KB LDS + VGPR<=64 -> 8 blocks/CU (32 waves/CU)
// for latency hiding; every FMA is v_pk_fma_f32.
__global__ __launch_bounds__(NTHREADS, 8)
void ssim_tile_kernel(const float* __restrict__ img1, const float* __restrict__ img2,
                      float* __restrict__ bsums, W22 wt) {
    __shared__ f32x4 sE[TH][LWE];   // 17,152 B
    __shared__ float redw[NTHREADS / 64];

    // XCD-aware bijective remap (NBLK % 8 == 0); sbid order: x-tile fastest,
    // then y-band, then plane -> halo rows reused within one XCD's L2.
    const int bid   = blockIdx.x;
    const int sbid  = (bid & 7) * (NBLK / 8) + (bid >> 3);
    const int xt    = sbid & 1;
    const int band  = (sbid >> 1) & (NBANDS - 1);
    const int plane = sbid >> 8;

    const int C0 = xt * TW;
    const int r0 = band * TH - KR;
    const float* __restrict__ p1 = img1 + (size_t)plane * (IMG_H * IMG_W);
    const float* __restrict__ p2 = img2 + (size_t)plane * (IMG_H * IMG_W);
    const int tid = threadIdx.x;
    const bool yint = (r0 >= 0) && (r0 + NR <= IMG_H);

    // ---- Phase A: vertical 11-tap conv, one column strip per thread ----
    // (threads 0..9 take a second strip for the 266-strip halo)
    for (int s = tid; s < NSTRIP; s += NTHREADS) {
        const int   col  = C0 - KR + s;
        const int   colc = min(max(col, 0), IMG_W - 1);
        const float sel  = (col >= 0 && col < IMG_W) ? 1.f : 0.f;
        const float* __restrict__ g1 = p1 + colc;
        const float* __restrict__ g2 = p2 + colc;

        float av[NR], bv[NR];
        if (yint) {
            #pragma unroll
            for (int j = 0; j < NR; ++j) {
                av[j] = g1[(r0 + j) * IMG_W];
                bv[j] = g2[(r0 + j) * IMG_W];
            }
        } else {
            #pragma unroll
            for (int j = 0; j < NR; ++j) {
                const int  rr  = r0 + j;
                const bool ok  = (rr >= 0) && (rr < IMG_H);   // block-uniform
                const int  rrc = min(max(rr, 0), IMG_H - 1);
                const float a = g1[rrc * IMG_W];
                const float b = g2[rrc * IMG_W];
                av[j] = ok ? a : 0.f;
                bv[j] = ok ? b : 0.f;
            }
        }
        // Force ALL loads in flight simultaneously (single statement each ->
        // no load may sink past it; one vmcnt wait instead of 14).
        asm volatile("" :: "v"(av[0]), "v"(av[1]), "v"(av[2]), "v"(av[3]),
                           "v"(av[4]), "v"(av[5]), "v"(av[6]), "v"(av[7]),
                           "v"(av[8]), "v"(av[9]), "v"(av[10]), "v"(av[11]),
                           "v"(av[12]), "v"(av[13]));
        asm volatile("" :: "v"(bv[0]), "v"(bv[1]), "v"(bv[2]), "v"(bv[3]),
                           "v"(bv[4]), "v"(bv[5]), "v"(bv[6]), "v"(bv[7]),
                           "v"(bv[8]), "v"(bv[9]), "v"(bv[10]), "v"(bv[11]),
                           "v"(bv[12]), "v"(bv[13]));

        f32x2 accm[TH], accs[TH];
        #pragma unroll
        for (int r = 0; r < TH; ++r) { accm[r] = (f32x2){0.f, 0.f}; accs[r] = (f32x2){0.f, 0.f}; }

        #pragma unroll
        for (int j = 0; j < NR; ++j) {
            const float a = av[j], b = bv[j];
            f32x2 mv; mv.x = a;                 mv.y = b;
            f32x2 pv; pv.x = fmaf(a, a, b * b); pv.y = a * b;
            #pragma unroll
            for (int r = 0; r < TH; ++r) {
                const int k = j - r;                          // compile-time
                if (k >= 0 && k < KS) {
                    f32x2 wv; wv.x = wt.w[2*k]; wv.y = wt.w[2*k + 1];
                    accm[r] = __builtin_elementwise_fma(wv, mv, accm[r]);
                    accs[r] = __builtin_elementwise_fma(wv, pv, accs[r]);
                }
            }
        }

        const f32x2 sel2 = {sel, sel};          // zero x-out-of-image strips
        const int slot = swz(s);
        #pragma unroll
        for (int r = 0; r < TH; ++r) {
            const f32x2 m = accm[r] * sel2;
            const f32x2 v = accs[r] * sel2;
            sE[r][slot] = (f32x4){m.x, m.y, v.x, v.y};
        }
    }
    __syncthreads();

    // ---- Phase B: horizontal conv + SSIM map; 1 row x 4 cols per thread.
    //      Streamed in two elem batches (8 + 6) to keep VGPR <= 64. ----
    const float C1f = 0.0001f;   // 0.01^2
    const float C2f = 0.0009f;   // 0.03^2
    const int r  = tid >> 6;             // 4 rows x 64 lanes
    const int L  = tid & 63;
    const int e0 = L << 2;               // base elem; output col jj uses
                                         // elems e0+jj .. e0+jj+10
    f32x4 acc[4];
    #pragma unroll
    for (int jj = 0; jj < 4; ++jj) acc[jj] = (f32x4){0.f, 0.f, 0.f, 0.f};

    {
        f32x4 x[8];
        #pragma unroll
        for (int i = 0; i < 8; ++i) x[i] = sE[r][swz(e0 + i)];
        #pragma unroll
        for (int jj = 0; jj < 4; ++jj) {
            #pragma unroll
            for (int k = 0; k < KS; ++k) {
                if (jj + k < 8) {
                    f32x4 wv; wv.x = wt.w[2*k]; wv.y = wt.w[2*k+1];
                    wv.z = wt.w[2*k]; wv.w = wt.w[2*k+1];
                    acc[jj] = __builtin_elementwise_fma(wv, x[jj + k], acc[jj]);
                }
            }
        }
    }
    {
        f32x4 x[6];
        #pragma unroll
        for (int i = 0; i < 6; ++i) x[i] = sE[r][swz(e0 + 8 + i)];
        #pragma unroll
        for (int jj = 0; jj < 4; ++jj) {
            #pragma unroll
            for (int k = 0; k < KS; ++k) {
                if (jj + k >= 8) {
                    f32x4 wv; wv.x = wt.w[2*k]; wv.y = wt.w[2*k+1];
                    wv.z = wt.w[2*k]; wv.w = wt.w[2*k+1];
                    acc[jj] = __builtin_elementwise_fma(wv, x[jj + k - 8], acc[jj]);
                }
            }
        }
    }

    float lsum = 0.f;
    #pragma unroll
    for (int jj = 0; jj < 4; ++jj) {
        const float m1 = acc[jj].x, m2 = acc[jj].y;
        const float pp = acc[jj].z, ab = acc[jj].w;
        const float mu11 = m1 * m1;
        const float mu22 = m2 * m2;
        const float mu12 = m1 * m2;
        const float t     = mu11 + mu22;
        const float sigpp = pp - t;              // sigma1_sq + sigma2_sq
        const float sig12 = ab - mu12;
        const float num = fmaf(2.f, mu12, C1f) * fmaf(2.f, sig12, C2f);
        const float den = (t + C1f) * (sigpp + C2f);
        lsum = fmaf(num, __builtin_amdgcn_rcpf(den), lsum);
    }

    // ---- reduce: wave shuffle, then per-wave partials ----
    #pragma unroll
    for (int off = 32; off > 0; off >>= 1) lsum += __shfl_down(lsum, off);
    if ((tid & 63) == 0) redw[tid >> 6] = lsum;
    __syncthreads();
    if (tid == 0) {
        float t = 0.f;
        #pragma unroll
        for (int w = 0; w < NTHREADS / 64; ++w) t += redw[w];
        bsums[sbid] = t;
    }
}

// Final reduce in double (fp32 sequential sum of the 1.26e7-magnitude total
// would exceed the 2.6e-4 threshold).
__global__ __launch_bounds__(256)
void ssim_reduce_kernel(const float4* __restrict__ bsums, int n4,
                        float* __restrict__ out, double inv_count) {
    __shared__ double red[256];
    double acc = 0.0;
    for (int i = threadIdx.x; i < n4; i += 256) {
        const float4 v = bsums[i];
        acc += (double)v.x + (double)v.y + (double)v.z + (double)v.w;
    }
    red[threadIdx.x] = acc;
    __syncthreads();
    #pragma unroll
    for (int off = 128; off > 0; off >>= 1) {
        if (threadIdx.x < off) red[threadIdx.x] += red[threadIdx.x + off];
        __syncthreads();
    }
    if (threadIdx.x == 0) out[0] = (float)(red[0] * inv_count);
}

extern "C" void kernel_launch(void* const* d_in, const int* in_sizes, int n_in,
                              void* d_out, int out_size, void* d_ws, size_t ws_size,
                              hipStream_t stream) {
    const float* img1 = (const float*)d_in[0];
    const float* img2 = (const float*)d_in[1];
    float* out = (float*)d_out;
    float* bsums = (float*)d_ws;

    // Gaussian weights, computed in double like the numpy reference, cast to
    // f32, duplicated per tap (ready-made 64-bit SGPR pairs for pk_fma).
    W22 wt;
    {
        double g[KS], sum = 0.0;
        for (int i = 0; i < KS; ++i) {
            const double x = (double)(i - KR);
            g[i] = exp(-(x * x) / (2.0 * 1.5 * 1.5));
            sum += g[i];
        }
        for (int i = 0; i < KS; ++i) {
            wt.w[2*i]     = (float)(g[i] / sum);
            wt.w[2*i + 1] = (float)(g[i] / sum);
        }
    }

    ssim_tile_kernel<<<dim3(NBLK), NTHREADS, 0, stream>>>(img1, img2, bsums, wt);

    const double inv_count = 1.0 / ((double)NPLANES * IMG_H * IMG_W);
    ssim_reduce_kernel<<<1, 256, 0, stream>>>((const float4*)bsums, NBLK / 4,
                                              out, inv_count);
}

// Round 12
// 51.171 us; speedup vs baseline: 1.1904x; 1.1904x over previous
//
#include <hip/hip_runtime.h>
#include <math.h>

#define IMG_H 512
#define IMG_W 512
#define TW 256               // output cols per block
#define TH 4                 // output rows per block
#define KR 5                 // radius
#define KS 11                // taps
#define NR (TH + 2 * KR)     // 14 input rows per band
#define NSTRIP (TW + 2 * KR) // 266 staged columns (elems)
#define LWE 268              // padded elems per row
#define NTHREADS 256
#define NXT (IMG_W / TW)     // 2
#define NBANDS (IMG_H / TH)  // 128
#define NPLANES 48
#define NBLK (NXT * NBANDS * NPLANES)   // 12288, divisible by 8

typedef float f32x2 __attribute__((ext_vector_type(2)));
typedef float f32x4 __attribute__((ext_vector_type(4)));

struct W22 { float w[2 * KS]; };   // w[2k] == w[2k+1] == gaussian tap k

// 16B-elem XOR swizzle: elem e (one f32x4). Spreads bank quads so phase-B
// b128 reads (64B lane stride) and phase-A writes are conflict-free.
__device__ __forceinline__ int swz(int e) { return e ^ ((e >> 3) & 7); }

// Fused SSIM tile kernel: one 256x4 output tile per block, 256 threads.
// Single LDS field per staged elem: (conv_v(a), conv_v(b), conv_v(a^2+b^2),
// conv_v(ab)) as f32x4. 17.2 KB LDS + VGPR<=64 -> 8 blocks/CU (32 waves/CU);
// latency hiding via TLP (8 independent barrier-groups per CU).
// Every FMA is v_pk_fma_f32.
__global__ __launch_bounds__(NTHREADS, 8)
void ssim_tile_kernel(const float* __restrict__ img1, const float* __restrict__ img2,
                      float* __restrict__ bsums, W22 wt) {
    __shared__ f32x4 sE[TH][LWE];   // 17,152 B
    __shared__ float redw[NTHREADS / 64];

    // XCD-aware bijective remap (NBLK % 8 == 0); sbid order: x-tile fastest,
    // then y-band, then plane -> halo rows reused within one XCD's L2.
    const int bid   = blockIdx.x;
    const int sbid  = (bid & 7) * (NBLK / 8) + (bid >> 3);
    const int xt    = sbid & 1;
    const int band  = (sbid >> 1) & (NBANDS - 1);
    const int plane = sbid >> 8;

    const int C0 = xt * TW;
    const int r0 = band * TH - KR;
    const float* __restrict__ p1 = img1 + (size_t)plane * (IMG_H * IMG_W);
    const float* __restrict__ p2 = img2 + (size_t)plane * (IMG_H * IMG_W);
    const int tid = threadIdx.x;
    const bool yint = (r0 >= 0) && (r0 + NR <= IMG_H);

    // ---- Phase A: vertical 11-tap conv, one column strip per thread ----
    // (threads 0..9 take a second strip for the 266-strip halo)
    #pragma unroll
    for (int pass = 0; pass < 2; ++pass) {
        const int s = tid + pass * NTHREADS;
        if (pass == 0 || s < NSTRIP) {
            const int   col  = C0 - KR + s;
            const int   colc = min(max(col, 0), IMG_W - 1);
            const float sel  = (col >= 0 && col < IMG_W) ? 1.f : 0.f;
            const float* __restrict__ g1 = p1 + colc;
            const float* __restrict__ g2 = p2 + colc;

            float av[NR], bv[NR];
            if (yint) {
                #pragma unroll
                for (int j = 0; j < NR; ++j) {
                    av[j] = g1[(r0 + j) * IMG_W];
                    bv[j] = g2[(r0 + j) * IMG_W];
                }
            } else {
                #pragma unroll
                for (int j = 0; j < NR; ++j) {
                    const int  rr  = r0 + j;
                    const bool ok  = (rr >= 0) && (rr < IMG_H);   // block-uniform
                    const int  rrc = min(max(rr, 0), IMG_H - 1);
                    const float a = g1[rrc * IMG_W];
                    const float b = g2[rrc * IMG_W];
                    av[j] = ok ? a : 0.f;
                    bv[j] = ok ? b : 0.f;
                }
            }

            f32x2 accm[TH], accs[TH];
            #pragma unroll
            for (int r = 0; r < TH; ++r) {
                accm[r] = (f32x2){0.f, 0.f};
                accs[r] = (f32x2){0.f, 0.f};
            }

            #pragma unroll
            for (int j = 0; j < NR; ++j) {
                const float a = av[j], b = bv[j];
                f32x2 mv; mv.x = a;                 mv.y = b;
                f32x2 pv; pv.x = fmaf(a, a, b * b); pv.y = a * b;
                #pragma unroll
                for (int r = 0; r < TH; ++r) {
                    const int k = j - r;                          // compile-time
                    if (k >= 0 && k < KS) {
                        f32x2 wv; wv.x = wt.w[2*k]; wv.y = wt.w[2*k + 1];
                        accm[r] = __builtin_elementwise_fma(wv, mv, accm[r]);
                        accs[r] = __builtin_elementwise_fma(wv, pv, accs[r]);
                    }
                }
            }

            const f32x2 sel2 = {sel, sel};          // zero x-out-of-image strips
            const int slot = swz(s);
            #pragma unroll
            for (int r = 0; r < TH; ++r) {
                const f32x2 m = accm[r] * sel2;
                const f32x2 v = accs[r] * sel2;
                sE[r][slot] = (f32x4){m.x, m.y, v.x, v.y};
            }
        }
    }
    __syncthreads();

    // ---- Phase B: horizontal conv + SSIM map; 1 row x 4 cols per thread.
    //      Streamed in two elem batches (8 + 6) to keep VGPR bounded. ----
    const float C1f = 0.0001f;   // 0.01^2
    const float C2f = 0.0009f;   // 0.03^2
    const int r  = tid >> 6;             // 4 rows x 64 lanes
    const int L  = tid & 63;
    const int e0 = L << 2;               // base elem; output col jj uses
                                         // elems e0+jj .. e0+jj+10
    f32x4 acc[4];
    #pragma unroll
    for (int jj = 0; jj < 4; ++jj) acc[jj] = (f32x4){0.f, 0.f, 0.f, 0.f};

    {
        f32x4 x[8];
        #pragma unroll
        for (int i = 0; i < 8; ++i) x[i] = sE[r][swz(e0 + i)];
        #pragma unroll
        for (int jj = 0; jj < 4; ++jj) {
            #pragma unroll
            for (int k = 0; k < KS; ++k) {
                if (jj + k < 8) {
                    f32x4 wv; wv.x = wt.w[2*k]; wv.y = wt.w[2*k+1];
                    wv.z = wt.w[2*k]; wv.w = wt.w[2*k+1];
                    acc[jj] = __builtin_elementwise_fma(wv, x[jj + k], acc[jj]);
                }
            }
        }
    }
    {
        f32x4 x[6];
        #pragma unroll
        for (int i = 0; i < 6; ++i) x[i] = sE[r][swz(e0 + 8 + i)];
        #pragma unroll
        for (int jj = 0; jj < 4; ++jj) {
            #pragma unroll
            for (int k = 0; k < KS; ++k) {
                if (jj + k >= 8) {
                    f32x4 wv; wv.x = wt.w[2*k]; wv.y = wt.w[2*k+1];
                    wv.z = wt.w[2*k]; wv.w = wt.w[2*k+1];
                    acc[jj] = __builtin_elementwise_fma(wv, x[jj + k - 8], acc[jj]);
                }
            }
        }
    }

    float lsum = 0.f;
    #pragma unroll
    for (int jj = 0; jj < 4; ++jj) {
        const float m1 = acc[jj].x, m2 = acc[jj].y;
        const float pp = acc[jj].z, ab = acc[jj].w;
        const float mu11 = m1 * m1;
        const float mu22 = m2 * m2;
        const float mu12 = m1 * m2;
        const float t     = mu11 + mu22;
        const float sigpp = pp - t;              // sigma1_sq + sigma2_sq
        const float sig12 = ab - mu12;
        const float num = fmaf(2.f, mu12, C1f) * fmaf(2.f, sig12, C2f);
        const float den = (t + C1f) * (sigpp + C2f);
        lsum = fmaf(num, __builtin_amdgcn_rcpf(den), lsum);
    }

    // ---- reduce: wave shuffle, then per-wave partials ----
    #pragma unroll
    for (int off = 32; off > 0; off >>= 1) lsum += __shfl_down(lsum, off);
    if ((tid & 63) == 0) redw[tid >> 6] = lsum;
    __syncthreads();
    if (tid == 0) {
        float t = 0.f;
        #pragma unroll
        for (int w = 0; w < NTHREADS / 64; ++w) t += redw[w];
        bsums[sbid] = t;
    }
}

// Final reduce in double (fp32 sequential sum of the 1.26e7-magnitude total
// would exceed the 2.6e-4 threshold).
__global__ __launch_bounds__(256)
void ssim_reduce_kernel(const float4* __restrict__ bsums, int n4,
                        float* __restrict__ out, double inv_count) {
    __shared__ double red[256];
    double acc = 0.0;
    for (int i = threadIdx.x; i < n4; i += 256) {
        const float4 v = bsums[i];
        acc += (double)v.x + (double)v.y + (double)v.z + (double)v.w;
    }
    red[threadIdx.x] = acc;
    __syncthreads();
    #pragma unroll
    for (int off = 128; off > 0; off >>= 1) {
        if (threadIdx.x < off) red[threadIdx.x] += red[threadIdx.x + off];
        __syncthreads();
    }
    if (threadIdx.x == 0) out[0] = (float)(red[0] * inv_count);
}

extern "C" void kernel_launch(void* const* d_in, const int* in_sizes, int n_in,
                              void* d_out, int out_size, void* d_ws, size_t ws_size,
                              hipStream_t stream) {
    const float* img1 = (const float*)d_in[0];
    const float* img2 = (const float*)d_in[1];
    float* out = (float*)d_out;
    float* bsums = (float*)d_ws;

    // Gaussian weights, computed in double like the numpy reference, cast to
    // f32, duplicated per tap (ready-made 64-bit SGPR pairs for pk_fma).
    W22 wt;
    {
        double g[KS], sum = 0.0;
        for (int i = 0; i < KS; ++i) {
            const double x = (double)(i - KR);
            g[i] = exp(-(x * x) / (2.0 * 1.5 * 1.5));
            sum += g[i];
        }
        for (int i = 0; i < KS; ++i) {
            wt.w[2*i]     = (float)(g[i] / sum);
            wt.w[2*i + 1] = (float)(g[i] / sum);
        }
    }

    ssim_tile_kernel<<<dim3(NBLK), NTHREADS, 0, stream>>>(img1, img2, bsums, wt);

    const double inv_count = 1.0 / ((double)NPLANES * IMG_H * IMG_W);
    ssim_reduce_kernel<<<1, 256, 0, stream>>>((const float4*)bsums, NBLK / 4,
                                              out, inv_count);
}

// Round 13
// 47.322 us; speedup vs baseline: 1.2872x; 1.0813x over previous
//
#include <hip/hip_runtime.h>
#include <math.h>

#define IMG_H 512
#define IMG_W 512
#define TH 4                 // output rows per band
#define KR 5                 // radius
#define KS 11                // taps
#define NR (TH + 2 * KR)     // 14 input rows per band
#define LW2 524              // f32x2 elems per row: global cols -6..517 at e=col+6
#define NTHREADS 512
#define NPAIRS 64            // band pairs per plane (128 bands / 2)
#define NPLANES 48
#define NBLK (NPAIRS * NPLANES)   // 3072, divisible by 8

typedef float f32x2 __attribute__((ext_vector_type(2)));

struct W22 { float w[2 * KS]; };   // w[2k] == w[2k+1] == gaussian tap k

// 16B-unit XOR swizzle: u = f32x2-pair index within a row.
__device__ __forceinline__ int swz(int u) { return u ^ ((u >> 3) & 7); }

// Load one band's 14 rows for this thread's column (block-uniform row bounds).
__device__ __forceinline__ void load_band(const float* __restrict__ g1,
                                          const float* __restrict__ g2,
                                          int r0, float av[NR], float bv[NR]) {
    if (r0 >= 0 && r0 + NR <= IMG_H) {
        #pragma unroll
        for (int j = 0; j < NR; ++j) {
            av[j] = g1[(r0 + j) * IMG_W];
            bv[j] = g2[(r0 + j) * IMG_W];
        }
    } else {
        #pragma unroll
        for (int j = 0; j < NR; ++j) {
            const int  rr  = r0 + j;
            const bool ok  = (rr >= 0) && (rr < IMG_H);
            const int  rrc = min(max(rr, 0), IMG_H - 1);
            const float a = g1[rrc * IMG_W];
            const float b = g2[rrc * IMG_W];
            av[j] = ok ? a : 0.f;
            bv[j] = ok ? b : 0.f;
        }
    }
}

// Vertical 11-tap conv (packed pairs) + swizzled LDS store.
__device__ __forceinline__ void vconv_store(const float av[NR], const float bv[NR],
                                            const W22& wt,
                                            f32x2 (* __restrict__ sm)[LW2],
                                            f32x2 (* __restrict__ sv)[LW2],
                                            int slot) {
    f32x2 accm[TH], accs[TH];
    #pragma unroll
    for (int r = 0; r < TH; ++r) { accm[r] = (f32x2){0.f, 0.f}; accs[r] = (f32x2){0.f, 0.f}; }
    #pragma unroll
    for (int j = 0; j < NR; ++j) {
        const float a = av[j], b = bv[j];
        f32x2 mv; mv.x = a;                 mv.y = b;
        f32x2 pv; pv.x = fmaf(a, a, b * b); pv.y = a * b;
        #pragma unroll
        for (int r = 0; r < TH; ++r) {
            const int k = j - r;                          // compile-time
            if (k >= 0 && k < KS) {
                f32x2 wv; wv.x = wt.w[2*k]; wv.y = wt.w[2*k + 1];
                accm[r] = __builtin_elementwise_fma(wv, mv, accm[r]);
                accs[r] = __builtin_elementwise_fma(wv, pv, accs[r]);
            }
        }
    }
    #pragma unroll
    for (int r = 0; r < TH; ++r) {
        sm[r][slot] = accm[r];
        sv[r][slot] = accs[r];
    }
}

// Horizontal 11-tap conv + SSIM map; returns this thread's partial sum.
__device__ __forceinline__ float phaseB(const f32x2 (* __restrict__ sm)[LW2],
                                        const f32x2 (* __restrict__ sv)[LW2],
                                        const W22& wt, int tid, const int su[8]) {
    const float C1f = 0.0001f, C2f = 0.0009f;
    const int r = tid >> 7;              // 4 rows x 128 threads
    f32x2 cmu[4], csv[4];
    {
        f32x2 xm[16];
        const float4* rpm = (const float4*)&sm[r][0];
        #pragma unroll
        for (int i = 0; i < 8; ++i) {
            const float4 q = rpm[su[i]];
            xm[2*i]   = (f32x2){q.x, q.y};
            xm[2*i+1] = (f32x2){q.z, q.w};
        }
        #pragma unroll
        for (int j = 0; j < 4; ++j) {
            f32x2 w0; w0.x = wt.w[0]; w0.y = wt.w[1];
            f32x2 m = w0 * xm[j + 1];
            #pragma unroll
            for (int k = 1; k < KS; ++k) {
                f32x2 wv; wv.x = wt.w[2*k]; wv.y = wt.w[2*k + 1];
                m = __builtin_elementwise_fma(wv, xm[j + 1 + k], m);
            }
            cmu[j] = m;
        }
    }
    {
        f32x2 xs[16];
        const float4* rps = (const float4*)&sv[r][0];
        #pragma unroll
        for (int i = 0; i < 8; ++i) {
            const float4 q = rps[su[i]];
            xs[2*i]   = (f32x2){q.x, q.y};
            xs[2*i+1] = (f32x2){q.z, q.w};
        }
        #pragma unroll
        for (int j = 0; j < 4; ++j) {
            f32x2 w0; w0.x = wt.w[0]; w0.y = wt.w[1];
            f32x2 m = w0 * xs[j + 1];
            #pragma unroll
            for (int k = 1; k < KS; ++k) {
                f32x2 wv; wv.x = wt.w[2*k]; wv.y = wt.w[2*k + 1];
                m = __builtin_elementwise_fma(wv, xs[j + 1 + k], m);
            }
            csv[j] = m;
        }
    }
    float lsum = 0.f;
    #pragma unroll
    for (int j = 0; j < 4; ++j) {
        const float m1 = cmu[j].x, m2 = cmu[j].y;
        const float mu11 = m1 * m1;
        const float mu22 = m2 * m2;
        const float mu12 = m1 * m2;
        const float t     = mu11 + mu22;
        const float sigpp = csv[j].x - t;
        const float sig12 = csv[j].y - mu12;
        const float num = fmaf(2.f, mu12, C1f) * fmaf(2.f, sig12, C2f);
        const float den = (t + C1f) * (sigpp + C2f);
        lsum = fmaf(num, __builtin_amdgcn_rcpf(den), lsum);
    }
    return lsum;
}

// Fused SSIM: one block = TWO consecutive 512x4 bands, software-pipelined:
// load0 -> conv0 -> [issue load1] -> barrier -> phaseB0 (load1 in flight)
// -> conv1 -> barrier -> phaseB1. 67 KB LDS -> 2 blocks/CU; pipeline ILP
// replaces TLP. VGPR capped at 128 by launch_bounds (peak live ~100).
__global__ __launch_bounds__(NTHREADS, 4)
void ssim_tile_kernel(const float* __restrict__ img1, const float* __restrict__ img2,
                      float* __restrict__ bsums, W22 wt) {
    __shared__ __align__(16) f32x2 sm0[TH][LW2], sv0[TH][LW2];   // 33,536 B
    __shared__ __align__(16) f32x2 sm1[TH][LW2], sv1[TH][LW2];   // 33,536 B
    __shared__ float redw[NTHREADS / 64];

    // XCD-aware bijective remap: each XCD sweeps 6 whole planes in band order.
    const int bid   = blockIdx.x;
    const int sbid  = (bid & 7) * (NBLK / 8) + (bid >> 3);
    const int plane = sbid / NPAIRS;
    const int q     = sbid - plane * NPAIRS;          // band pair index

    const float* __restrict__ p1 = img1 + (size_t)plane * (IMG_H * IMG_W);
    const float* __restrict__ p2 = img2 + (size_t)plane * (IMG_H * IMG_W);
    const int tid = threadIdx.x;
    const int r0a = q * 8 - KR;          // band 2q rows
    const int r0b = q * 8 + TH - KR;     // band 2q+1 rows

    // Zero-fill the 12 alignment-halo cols in BOTH buffers.
    if (tid < 12) {
        const int e = (tid < 6) ? tid : (512 + tid);
        const int slot = swz(e >> 1) * 2 + (e & 1);
        #pragma unroll
        for (int r = 0; r < TH; ++r) {
            sm0[r][slot] = (f32x2){0.f, 0.f};
            sv0[r][slot] = (f32x2){0.f, 0.f};
            sm1[r][slot] = (f32x2){0.f, 0.f};
            sv1[r][slot] = (f32x2){0.f, 0.f};
        }
    }

    const float* __restrict__ g1 = p1 + tid;
    const float* __restrict__ g2 = p2 + tid;
    const int e = tid + 6;
    const int slot = swz(e >> 1) * 2 + (e & 1);

    // ---- band 0: load + vertical conv + store ----
    float av0[NR], bv0[NR];
    load_band(g1, g2, r0a, av0, bv0);
    vconv_store(av0, bv0, wt, sm0, sv0, slot);

    // ---- issue band 1 loads NOW; keep them live across phaseB0 ----
    float av1[NR], bv1[NR];
    load_band(g1, g2, r0b, av1, bv1);
    asm volatile("" :: "v"(av1[0]), "v"(av1[1]), "v"(av1[2]), "v"(av1[3]),
                       "v"(av1[4]), "v"(av1[5]), "v"(av1[6]), "v"(av1[7]),
                       "v"(av1[8]), "v"(av1[9]), "v"(av1[10]), "v"(av1[11]),
                       "v"(av1[12]), "v"(av1[13]));
    asm volatile("" :: "v"(bv1[0]), "v"(bv1[1]), "v"(bv1[2]), "v"(bv1[3]),
                       "v"(bv1[4]), "v"(bv1[5]), "v"(bv1[6]), "v"(bv1[7]),
                       "v"(bv1[8]), "v"(bv1[9]), "v"(bv1[10]), "v"(bv1[11]),
                       "v"(bv1[12]), "v"(bv1[13]));

    __syncthreads();

    // Hoisted swizzled unit indices (shared by both phase-B calls).
    const int L  = tid & 127;
    const int u0 = L << 1;
    int su[8];
    #pragma unroll
    for (int i = 0; i < 8; ++i) su[i] = swz(u0 + i);

    // ---- phase B band 0 (band-1 loads in flight underneath) ----
    float lsum = phaseB(sm0, sv0, wt, tid, su);

    // ---- band 1: vertical conv + store ----
    vconv_store(av1, bv1, wt, sm1, sv1, slot);
    __syncthreads();

    // ---- phase B band 1 ----
    lsum += phaseB(sm1, sv1, wt, tid, su);

    // ---- reduce: wave shuffle, then per-wave partials ----
    #pragma unroll
    for (int off = 32; off > 0; off >>= 1) lsum += __shfl_down(lsum, off);
    if ((tid & 63) == 0) redw[tid >> 6] = lsum;
    __syncthreads();
    if (tid == 0) {
        float t = 0.f;
        #pragma unroll
        for (int w = 0; w < NTHREADS / 64; ++w) t += redw[w];
        bsums[sbid] = t;
    }
}

// Final reduce in double (fp32 sequential sum of the 1.26e7-magnitude total
// would exceed the 2.6e-4 threshold).
__global__ __launch_bounds__(256)
void ssim_reduce_kernel(const float4* __restrict__ bsums, int n4,
                        float* __restrict__ out, double inv_count) {
    __shared__ double red[256];
    double acc = 0.0;
    for (int i = threadIdx.x; i < n4; i += 256) {
        const float4 v = bsums[i];
        acc += (double)v.x + (double)v.y + (double)v.z + (double)v.w;
    }
    red[threadIdx.x] = acc;
    __syncthreads();
    #pragma unroll
    for (int off = 128; off > 0; off >>= 1) {
        if (threadIdx.x < off) red[threadIdx.x] += red[threadIdx.x + off];
        __syncthreads();
    }
    if (threadIdx.x == 0) out[0] = (float)(red[0] * inv_count);
}

extern "C" void kernel_launch(void* const* d_in, const int* in_sizes, int n_in,
                              void* d_out, int out_size, void* d_ws, size_t ws_size,
                              hipStream_t stream) {
    const float* img1 = (const float*)d_in[0];
    const float* img2 = (const float*)d_in[1];
    float* out = (float*)d_out;
    float* bsums = (float*)d_ws;

    // Gaussian weights, computed in double like the numpy reference, cast to
    // f32, duplicated per tap (ready-made 64-bit SGPR pairs for pk_fma).
    W22 wt;
    {
        double g[KS], sum = 0.0;
        for (int i = 0; i < KS; ++i) {
            const double x = (double)(i - KR);
            g[i] = exp(-(x * x) / (2.0 * 1.5 * 1.5));
            sum += g[i];
        }
        for (int i = 0; i < KS; ++i) {
            wt.w[2*i]     = (float)(g[i] / sum);
            wt.w[2*i + 1] = (float)(g[i] / sum);
        }
    }

    ssim_tile_kernel<<<dim3(NBLK), NTHREADS, 0, stream>>>(img1, img2, bsums, wt);

    const double inv_count = 1.0 / ((double)NPLANES * IMG_H * IMG_W);
    ssim_reduce_kernel<<<1, 256, 0, stream>>>((const float4*)bsums, NBLK / 4,
                                              out, inv_count);
}

// Round 14
// 40.686 us; speedup vs baseline: 1.4971x; 1.1631x over previous
//
#include <hip/hip_runtime.h>
#include <math.h>

#define IMG_H 512
#define IMG_W 512
#define TH 8                 // output rows per band
#define KR 5                 // radius
#define KS 11                // taps
#define NR (TH + 2 * KR)     // 18 input rows per band
#define LWE 524              // f32x4 elems per row: global cols -6..517 at e=col+6
#define NTHREADS 512
#define NBANDS (IMG_H / TH)  // 64
#define NPLANES 48
#define NBLK (NBANDS * NPLANES)   // 3072, divisible by 8

typedef float f32x2 __attribute__((ext_vector_type(2)));
typedef float f32x4 __attribute__((ext_vector_type(4)));

struct W22 { float w[2 * KS]; };   // w[2k] == w[2k+1] == gaussian tap k

// 16B-elem XOR swizzle (elem = one f32x4). Phase-B reads have lane stride 8
// elems (128B) -> all lanes would hit one bank quad; XOR of bits 3..5 into
// bits 0..2 spreads 64 lanes across all 8 quads (dense). Phase-A stores are
// lane-stride-1 and stay dense. Never escapes an aligned 8-elem block.
__device__ __forceinline__ int swz(int e) { return e ^ ((e >> 3) & 7); }

// Fused SSIM band kernel: one 512x8 full-width band per block, 512 threads.
// LDS: ONE swizzled f32x4 field: (conv_v(a), conv_v(b), conv_v(a^2+b^2),
// conv_v(ab)). Phase A: one column per thread (no tail). Phase B: one row x 8
// consecutive cols per thread -> 18 b128 reads per 8 outputs (2.25/output,
// ~half of the 4-output scheme) -- attacks the LDS-pipe bound.
// 67 KB LDS -> 2 blocks/CU; VGPR capped 128 by launch_bounds(512,4).
__global__ __launch_bounds__(NTHREADS, 4)
void ssim_tile_kernel(const float* __restrict__ img1, const float* __restrict__ img2,
                      float* __restrict__ bsums, W22 wt) {
    __shared__ f32x4 sE[TH][LWE];   // 67,072 B
    __shared__ float redw[NTHREADS / 64];

    // XCD-aware bijective remap (NBLK % 8 == 0): each XCD sweeps 6 whole
    // planes in ascending band order -> band halos hit its own L2.
    const int bid   = blockIdx.x;
    const int sbid  = (bid & 7) * (NBLK / 8) + (bid >> 3);
    const int plane = sbid >> 6;              // sbid / NBANDS
    const int band  = sbid & (NBANDS - 1);

    const int r0 = band * TH - KR;
    const float* __restrict__ p1 = img1 + (size_t)plane * (IMG_H * IMG_W);
    const float* __restrict__ p2 = img2 + (size_t)plane * (IMG_H * IMG_W);
    const int tid = threadIdx.x;

    // Zero-fill the 12 alignment-halo elems (e 0..5 = cols -6..-1, 518..523)
    // in all 8 rows (96 writes by threads 0..127).
    if (tid < 128) {
        const int h = tid & 15;
        if (h < 12) {
            const int r = tid >> 4;                    // 0..7
            const int e = (h < 6) ? h : (512 + h);
            sE[r][swz(e)] = (f32x4){0.f, 0.f, 0.f, 0.f};
        }
    }

    // ---- Phase A: vertical 11-tap conv, one column per thread ----
    float av[NR], bv[NR];
    {
        const float* __restrict__ g1 = p1 + tid;
        const float* __restrict__ g2 = p2 + tid;
        if (r0 >= 0 && r0 + NR <= IMG_H) {
            #pragma unroll
            for (int j = 0; j < NR; ++j) {
                av[j] = g1[(r0 + j) * IMG_W];
                bv[j] = g2[(r0 + j) * IMG_W];
            }
        } else {
            #pragma unroll
            for (int j = 0; j < NR; ++j) {
                const int  rr  = r0 + j;
                const bool ok  = (rr >= 0) && (rr < IMG_H);   // block-uniform
                const int  rrc = min(max(rr, 0), IMG_H - 1);
                const float a = g1[rrc * IMG_W];
                const float b = g2[rrc * IMG_W];
                av[j] = ok ? a : 0.f;
                bv[j] = ok ? b : 0.f;
            }
        }
    }

    f32x4 acc[TH];
    #pragma unroll
    for (int r = 0; r < TH; ++r) acc[r] = (f32x4){0.f, 0.f, 0.f, 0.f};

    #pragma unroll
    for (int j = 0; j < NR; ++j) {
        const float a = av[j], b = bv[j];
        f32x4 pv; pv.x = a; pv.y = b;
        pv.z = fmaf(a, a, b * b); pv.w = a * b;
        #pragma unroll
        for (int r = 0; r < TH; ++r) {
            const int k = j - r;                      // compile-time
            if (k >= 0 && k < KS) {
                f32x4 wv; wv.x = wt.w[2*k]; wv.y = wt.w[2*k + 1];
                wv.z = wt.w[2*k]; wv.w = wt.w[2*k + 1];
                acc[r] = __builtin_elementwise_fma(wv, pv, acc[r]);
            }
        }
    }
    {
        const int slot = swz(tid + 6);
        #pragma unroll
        for (int r = 0; r < TH; ++r) sE[r][slot] = acc[r];
    }
    __syncthreads();

    // ---- Phase B: horizontal conv + SSIM map; 1 row x 8 consecutive cols ----
    const float C1f = 0.0001f;   // 0.01^2
    const float C2f = 0.0009f;   // 0.03^2
    const int g  = tid >> 6;             // 8 rows x 64 lanes
    const int L  = tid & 63;
    const int eb = (L << 3) + 1;         // cols 8L..8L+7 need elems eb..eb+17

    f32x4 x[18];
    #pragma unroll
    for (int i = 0; i < 18; ++i) x[i] = sE[g][swz(eb + i)];

    float lsum = 0.f;
    #pragma unroll
    for (int jj = 0; jj < 8; ++jj) {
        f32x4 c;
        {
            f32x4 wv; wv.x = wt.w[0]; wv.y = wt.w[1];
            wv.z = wt.w[0]; wv.w = wt.w[1];
            c = wv * x[jj];
        }
        #pragma unroll
        for (int k = 1; k < KS; ++k) {
            f32x4 wv; wv.x = wt.w[2*k]; wv.y = wt.w[2*k + 1];
            wv.z = wt.w[2*k]; wv.w = wt.w[2*k + 1];
            c = __builtin_elementwise_fma(wv, x[jj + k], c);
        }
        const float m1 = c.x, m2 = c.y;
        const float pp = c.z, ab = c.w;
        const float mu11 = m1 * m1;
        const float mu22 = m2 * m2;
        const float mu12 = m1 * m2;
        const float t     = mu11 + mu22;
        const float sigpp = pp - t;              // sigma1_sq + sigma2_sq
        const float sig12 = ab - mu12;
        const float num = fmaf(2.f, mu12, C1f) * fmaf(2.f, sig12, C2f);
        const float den = (t + C1f) * (sigpp + C2f);
        lsum = fmaf(num, __builtin_amdgcn_rcpf(den), lsum);
    }

    // ---- reduce: wave shuffle, then per-wave partials ----
    #pragma unroll
    for (int off = 32; off > 0; off >>= 1) lsum += __shfl_down(lsum, off);
    if ((tid & 63) == 0) redw[tid >> 6] = lsum;
    __syncthreads();
    if (tid == 0) {
        float t = 0.f;
        #pragma unroll
        for (int w = 0; w < NTHREADS / 64; ++w) t += redw[w];
        bsums[sbid] = t;
    }
}

// Final reduce in double (fp32 sequential sum of the 1.26e7-magnitude total
// would exceed the 2.6e-4 threshold).
__global__ __launch_bounds__(256)
void ssim_reduce_kernel(const float4* __restrict__ bsums, int n4,
                        float* __restrict__ out, double inv_count) {
    __shared__ double red[256];
    double acc = 0.0;
    for (int i = threadIdx.x; i < n4; i += 256) {
        const float4 v = bsums[i];
        acc += (double)v.x + (double)v.y + (double)v.z + (double)v.w;
    }
    red[threadIdx.x] = acc;
    __syncthreads();
    #pragma unroll
    for (int off = 128; off > 0; off >>= 1) {
        if (threadIdx.x < off) red[threadIdx.x] += red[threadIdx.x + off];
        __syncthreads();
    }
    if (threadIdx.x == 0) out[0] = (float)(red[0] * inv_count);
}

extern "C" void kernel_launch(void* const* d_in, const int* in_sizes, int n_in,
                              void* d_out, int out_size, void* d_ws, size_t ws_size,
                              hipStream_t stream) {
    const float* img1 = (const float*)d_in[0];
    const float* img2 = (const float*)d_in[1];
    float* out = (float*)d_out;
    float* bsums = (float*)d_ws;

    // Gaussian weights, computed in double like the numpy reference, cast to
    // f32, duplicated per tap (ready-made 64-bit SGPR pairs for pk_fma).
    W22 wt;
    {
        double g[KS], sum = 0.0;
        for (int i = 0; i < KS; ++i) {
            const double x = (double)(i - KR);
            g[i] = exp(-(x * x) / (2.0 * 1.5 * 1.5));
            sum += g[i];
        }
        for (int i = 0; i < KS; ++i) {
            wt.w[2*i]     = (float)(g[i] / sum);
            wt.w[2*i + 1] = (float)(g[i] / sum);
        }
    }

    ssim_tile_kernel<<<dim3(NBLK), NTHREADS, 0, stream>>>(img1, img2, bsums, wt);

    const double inv_count = 1.0 / ((double)NPLANES * IMG_H * IMG_W);
    ssim_reduce_kernel<<<1, 256, 0, stream>>>((const float4*)bsums, NBLK / 4,
                                              out, inv_count);
}